// Round 3
// baseline (273.695 us; speedup 1.0000x reference)
//
#include <hip/hip_runtime.h>
#include <hip/hip_bf16.h>
#include <stdint.h>

typedef short bf16x8 __attribute__((ext_vector_type(8)));
typedef float f32x4  __attribute__((ext_vector_type(4)));

#define NB   8
#define NC   256
#define NO   256
#define HH   64
#define WW   64
#define NPIX 4096
#define KTOT 2304
#define NKC  72

// workspace layout (bytes)
#define XN_OFF  0u
#define XN_SZ   (NB*NPIX*NC*2u)
#define WP_OFF  (XN_OFF + XN_SZ)
#define WP_SZ   (KTOT*NO*2u)
#define WPO_OFF (WP_OFF + WP_SZ)
#define WPO_SZ  (KTOT*32u*2u)
#define OM_OFF  (WPO_OFF + WPO_SZ)
#define OM_SZ   (NB*NPIX*32u*4u)
#define PY_OFF  (OM_OFF + OM_SZ)
#define CO_SZ   (NB*9u*NPIX*4u)
#define PX_OFF  (PY_OFF + CO_SZ)
#define MK_OFF  (PX_OFF + CO_SZ)

__device__ __forceinline__ float b2f(short s) {
    union { unsigned u; float f; } z; z.u = ((unsigned)(unsigned short)s) << 16; return z.f;
}
__device__ __forceinline__ short f2b(float f) {
    __hip_bfloat16 h = __float2bfloat16(f);
    short s; __builtin_memcpy(&s, &h, 2); return s;
}

// ---------------- kernel 1: x (NCHW f32) -> xn (NHWC bf16), vectorized ----------------
__global__ void pack_x(const float* __restrict__ x, unsigned short* __restrict__ xn) {
    __shared__ float tile[64][65];
    int blk = blockIdx.x;                  // 2048 = 8b * 4ct * 64pt
    int pt = blk & 63, ct = (blk >> 6) & 3, b = blk >> 8;
    int t = threadIdx.x;
    int ci = t >> 4, p4 = (t & 15) * 4;
    const float* src = x + ((size_t)(b*NC + ct*64))*NPIX + (size_t)pt*64;
#pragma unroll
    for (int j = 0; j < 4; ++j) {
        f32x4 v = *(const f32x4*)(src + (size_t)(ci + 16*j)*NPIX + p4);
        tile[ci + 16*j][p4+0] = v[0];
        tile[ci + 16*j][p4+1] = v[1];
        tile[ci + 16*j][p4+2] = v[2];
        tile[ci + 16*j][p4+3] = v[3];
    }
    __syncthreads();
    int c8 = (t & 7) * 8, pj0 = t >> 3;    // pj0 0..31
    unsigned short* dst = xn + ((size_t)b*NPIX + (size_t)pt*64)*NC + ct*64 + c8;
#pragma unroll
    for (int j = 0; j < 2; ++j) {
        int pj = pj0 + 32*j;
        bf16x8 o;
#pragma unroll
        for (int e = 0; e < 8; ++e) o[e] = f2b(tile[c8 + e][pj]);
        *(bf16x8*)(dst + (size_t)pj*NC) = o;
    }
}

// ---------------- kernel 2: pack main weight into B-fragment order ----------------
__global__ void pack_w(const float* __restrict__ weight, unsigned short* __restrict__ wp) {
    int idx = blockIdx.x*256 + threadIdx.x;
    int e = idx & 7, l = (idx >> 3) & 63, nt = (idx >> 9) & 15, kc = idx >> 13;
    int k  = kc*32 + 8*(l >> 4) + e;
    int k2 = k >> 8, c = k & 255;
    int ky = k2 / 3, kx = k2 - 3*ky;
    int o  = nt*16 + (l & 15);
    float v = weight[(size_t)(o*NC + c)*9 + ky*3 + kx];
    wp[idx] = (unsigned short)f2b(v);
}

// ---------------- kernel 3: pack offset-conv weight (N padded 27->32) ----------------
__global__ void pack_wo(const float* __restrict__ w_off, unsigned short* __restrict__ wpo) {
    int idx = blockIdx.x*256 + threadIdx.x;
    int e = idx & 7, l = (idx >> 3) & 63, nt = (idx >> 9) & 1, kc = idx >> 10;
    int k  = kc*32 + 8*(l >> 4) + e;
    int k2 = k >> 8, c = k & 255;
    int ky = k2 / 3, kx = k2 - 3*ky;
    int n  = nt*16 + (l & 15);
    float v = (n < 27) ? w_off[(size_t)(n*NC + c)*9 + ky*3 + kx] : 0.0f;
    wpo[idx] = (unsigned short)f2b(v);
}

// ---------------- kernel 4: offset conv — depth-3 register pipeline, branchless ------
__launch_bounds__(128, 4)
__global__ void off_conv(const unsigned short* __restrict__ xn,
                         const unsigned short* __restrict__ wpo,
                         float* __restrict__ om) {
    int bid = blockIdx.x;                 // 1024; batch per XCD
    int b = bid & 7, mt = bid >> 3;       // mt 0..127
    int t = threadIdx.x, wv = t >> 6, l = t & 63, g = l >> 4;
    int pix = mt*32 + wv*16 + (l & 15);
    int y = pix >> 6, xx = pix & 63;
    f32x4 acc0 = {0.f,0.f,0.f,0.f}, acc1 = {0.f,0.f,0.f,0.f};
    const char* xc = (const char*)(xn + (size_t)b*NPIX*NC);
    const bf16x8* wpf = (const bf16x8*)wpo;
    const bf16x8 zero8 = {0,0,0,0,0,0,0,0};

    auto aaddr = [&](int kc)->const char* {
        int k2 = kc >> 3, cc = kc & 7;
        int ky = k2 / 3, kx = k2 - 3*ky;
        int sy = y + ky - 1, sx = xx + kx - 1;
        int cs = min(max(sy,0),HH-1)*WW + min(max(sx,0),WW-1);
        return xc + ((size_t)cs*NC + cc*32 + g*8)*2;
    };
    auto avalid = [&](int kc)->bool {
        int k2 = kc >> 3;
        int ky = k2 / 3, kx = k2 - 3*ky;
        int sy = y + ky - 1, sx = xx + kx - 1;
        return (sy>=0)&(sy<HH)&(sx>=0)&(sx<WW);
    };

    bf16x8 a[3], w0[3], w1[3];
    bool v[3];
#pragma unroll
    for (int s = 0; s < 3; ++s) {
        a[s]  = *(const bf16x8*)aaddr(s);
        w0[s] = wpf[(size_t)(s*2)*64 + l];
        w1[s] = wpf[(size_t)(s*2+1)*64 + l];
        v[s]  = avalid(s);
    }
#pragma unroll
    for (int kc = 0; kc < NKC; ++kc) {
        int s = kc % 3;                   // static under full unroll
        bf16x8 au = v[s] ? a[s] : zero8;
        acc0 = __builtin_amdgcn_mfma_f32_16x16x32_bf16(au, w0[s], acc0, 0, 0, 0);
        acc1 = __builtin_amdgcn_mfma_f32_16x16x32_bf16(au, w1[s], acc1, 0, 0, 0);
        int kp = kc + 3;
        if (kp < NKC) {
            a[s]  = *(const bf16x8*)aaddr(kp);
            w0[s] = wpf[(size_t)(kp*2)*64 + l];
            w1[s] = wpf[(size_t)(kp*2+1)*64 + l];
            v[s]  = avalid(kp);
        }
    }
#pragma unroll
    for (int r = 0; r < 4; ++r) {
        int pm = mt*32 + wv*16 + 4*g + r;
        om[((size_t)b*NPIX + pm)*32 +      (l & 15)] = acc0[r];
        om[((size_t)b*NPIX + pm)*32 + 16 + (l & 15)] = acc1[r];
    }
}

// ---------------- kernel 5: om -> sampling coords (py, px, mask) ----------------
__global__ void coords_k(const float* __restrict__ om, const float* __restrict__ b_off,
                         float* __restrict__ py, float* __restrict__ px,
                         float* __restrict__ mk) {
    int idx = blockIdx.x*256 + threadIdx.x;
    if (idx >= NB*9*NPIX) return;
    int pix = idx & 4095;
    int k   = (idx >> 12) % 9;
    int b   = idx / (9*NPIX);
    const float* omp = om + ((size_t)b*NPIX + pix)*32;
    float dy = omp[2*k]     + b_off[2*k];
    float dx = omp[2*k + 1] + b_off[2*k + 1];
    float m  = omp[18 + k]  + b_off[18 + k];
    float yy = (float)(pix >> 6) - 1.0f + (float)(k / 3) + dy;
    float xv = (float)(pix & 63) - 1.0f + (float)(k % 3) + dx;
    py[idx] = yy;
    px[idx] = xv;
    mk[idx] = 1.0f / (1.0f + __expf(-m));
}

// ---------------- kernel 6: main deformable conv -----------------------------------
// 1024 blocks (batch-per-XCD), 4 waves, M=64 (16 pix/wave), N=128 (8 frags).
// Counted-vmcnt pipeline: depth-2 corners (parity ping-pong regs), depth-2 W stage
// (3 LDS buffers), 1 raw s_barrier/iter, vmcnt never drained to 0 in the loop.
__launch_bounds__(256, 4)
__global__ void dcn_main(const unsigned short* __restrict__ xn,
                         const unsigned short* __restrict__ wpack,
                         const float* __restrict__ pyA,
                         const float* __restrict__ pxA,
                         const float* __restrict__ mkA,
                         const float* __restrict__ bias,
                         float* __restrict__ out) {
    __shared__ unsigned short lds[3][4096];       // 3 x 8KB
    int bid = blockIdx.x;
    int b   = bid & 7;                            // batch per XCD
    int loc = bid >> 3;                           // 0..127
    int mt  = loc >> 1, nh = loc & 1;
    int t = threadIdx.x, wv = t >> 6, l = t & 63, g = l >> 4;
    int pix0 = mt*64 + wv*16 + (l & 15);

    f32x4 acc[8];
#pragma unroll
    for (int i = 0; i < 8; ++i) acc[i] = f32x4{0.f,0.f,0.f,0.f};

    const char* xc = (const char*)(xn + (size_t)b*NPIX*NC);
    const unsigned short* wpb = wpack + nh*4096 + wv*1024 + l*8;

    float cw[4], ncw[4];
    const char *bp[4], *nbp[4];
    float npy, npx, nm;

    auto coord_compute = [&](float py, float px, float m, float* cwf, const char** bpf) {
        float y0f = floorf(py), x0f = floorf(px);
        float ly = py - y0f, lx = px - x0f;
        int iy0 = (int)y0f, ix0 = (int)x0f;
        int iy1 = iy0 + 1,  ix1 = ix0 + 1;
        bool vy0 = (iy0 >= 0) & (iy0 < HH);
        bool vy1 = (iy1 >= 0) & (iy1 < HH);
        bool vx0 = (ix0 >= 0) & (ix0 < WW);
        bool vx1 = (ix1 >= 0) & (ix1 < WW);
        float wy0 = (1.f - ly) * m, wy1 = ly * m;
        cwf[0] = (vy0 & vx0) ? wy0 * (1.f - lx) : 0.f;
        cwf[1] = (vy0 & vx1) ? wy0 * lx         : 0.f;
        cwf[2] = (vy1 & vx0) ? wy1 * (1.f - lx) : 0.f;
        cwf[3] = (vy1 & vx1) ? wy1 * lx         : 0.f;
        int cy0 = min(max(iy0,0),HH-1), cy1 = min(max(iy1,0),HH-1);
        int cx0 = min(max(ix0,0),WW-1), cx1 = min(max(ix1,0),WW-1);
        bpf[0] = xc + ((size_t)(cy0*WW + cx0)*NC + g*8)*2;
        bpf[1] = xc + ((size_t)(cy0*WW + cx1)*NC + g*8)*2;
        bpf[2] = xc + ((size_t)(cy1*WW + cx0)*NC + g*8)*2;
        bpf[3] = xc + ((size_t)(cy1*WW + cx1)*NC + g*8)*2;
    };

#define STAGEW(bufi, kcs) do {                                                         \
        const unsigned short* _gs = wpb + (size_t)(kcs)*8192;                          \
        unsigned short* _ld = &lds[0][0] + (size_t)(bufi)*4096 + wv*1024;              \
        _Pragma("unroll")                                                              \
        for (int _i = 0; _i < 2; ++_i) {                                               \
            __builtin_amdgcn_global_load_lds(                                          \
                (const __attribute__((address_space(1))) unsigned int*)(_gs + _i*512), \
                (__attribute__((address_space(3))) unsigned int*)(_ld + _i*512),       \
                16, 0, 0);                                                             \
        }                                                                              \
    } while (0)

    // ---- prologue: coords(k2=0), corners(0)->cA, stage(0), corners(1)->cB, stage(1)
    {
        int ci = (b*9 << 12) + pix0;
        coord_compute(pyA[ci], pxA[ci], mkA[ci], cw, bp);
    }
    bf16x8 cA[4], cB[4];
#pragma unroll
    for (int c = 0; c < 4; ++c) cA[c] = *(const bf16x8*)bp[c];         // corners(0)
    STAGEW(0, 0);
#pragma unroll
    for (int c = 0; c < 4; ++c) cB[c] = *(const bf16x8*)(bp[c] + 64);  // corners(1)
    STAGEW(1, 1);
    __builtin_amdgcn_sched_barrier(0);
    asm volatile("s_waitcnt vmcnt(6)" ::: "memory");   // corners(0)+stage(0) done
    __builtin_amdgcn_s_barrier();
    __builtin_amdgcn_sched_barrier(0);

    int rb = 0, sb = 2;   // read buffer = kc%3 ; stage target = (kc+2)%3
    for (int k2 = 0; k2 < 9; ++k2) {
        int k2n = (k2 < 8) ? k2 + 1 : 8;
#pragma unroll
        for (int cc = 0; cc < 8; ++cc) {
            int kc = k2*8 + cc;
            if (cc == 1) {                         // load next-k2 coords (3 VMEM)
                int ci = ((b*9 + k2n) << 12) + pix0;
                npy = pyA[ci]; npx = pxA[ci]; nm = mkA[ci];
            }
            // blend corners(kc) -> A-frag  (corners certified by prev iter's vmcnt)
            bf16x8 af;
#pragma unroll
            for (int e = 0; e < 8; ++e) {
                const bf16x8* S = (cc & 1) ? cB : cA;
                float vv = cw[0]*b2f(S[0][e]) + cw[1]*b2f(S[1][e])
                         + cw[2]*b2f(S[2][e]) + cw[3]*b2f(S[3][e]);
                af[e] = f2b(vv);
            }
            const bf16x8* bl = (const bf16x8*)(&lds[0][0] + (size_t)rb*4096);
#pragma unroll
            for (int nt = 0; nt < 8; ++nt)
                acc[nt] = __builtin_amdgcn_mfma_f32_16x16x32_bf16(af, bl[nt*64 + l], acc[nt], 0, 0, 0);
            if (cc == 4) coord_compute(npy, npx, nm, ncw, nbp);
            // issue corners(kc+2) into the parity set just consumed (no copies)
            if (cc <= 5) {
#pragma unroll
                for (int c = 0; c < 4; ++c)
                    ((cc & 1) ? cB : cA)[c] = *(const bf16x8*)(bp[c] + (cc+2)*64);
            } else if (cc == 6) {
#pragma unroll
                for (int c = 0; c < 4; ++c) cA[c] = *(const bf16x8*)(nbp[c]);
            } else {
#pragma unroll
                for (int c = 0; c < 4; ++c) cB[c] = *(const bf16x8*)(nbp[c] + 64);
            }
            // stage W chunk kc+2 (clamped; trailing redundant stages are harmless)
            int kcs = kc + 2; if (kcs > NKC-1) kcs = NKC-1;
            STAGEW(sb, kcs);
            if (cc == 7) {
#pragma unroll
                for (int c = 0; c < 4; ++c) { cw[c] = ncw[c]; bp[c] = nbp[c]; }
            }
            sb = rb; rb = (rb == 2) ? 0 : rb + 1;
            __builtin_amdgcn_sched_barrier(0);
            if (cc == 1) asm volatile("s_waitcnt vmcnt(9)" ::: "memory");
            else         asm volatile("s_waitcnt vmcnt(6)" ::: "memory");
            __builtin_amdgcn_s_barrier();
            __builtin_amdgcn_sched_barrier(0);
        }
    }
#undef STAGEW
    // keep trailing corner loads alive so DCE can't break the vmcnt counts
    asm volatile("" :: "v"(cA[0]), "v"(cA[1]), "v"(cA[2]), "v"(cA[3]),
                       "v"(cB[0]), "v"(cB[1]), "v"(cB[2]), "v"(cB[3]));
    // drain trailing global_load_lds before workgroup exit (LDS may be reassigned)
    asm volatile("s_waitcnt vmcnt(0)" ::: "memory");

    int pmbase = mt*64 + wv*16 + 4*g;
#pragma unroll
    for (int nt = 0; nt < 8; ++nt) {
        int o = nh*128 + nt*16 + (l & 15);
        float bv = bias[o];
        f32x4 r = acc[nt] + bv;
        *(f32x4*)(out + ((size_t)(b*NO + o))*NPIX + pmbase) = r;
    }
}

extern "C" void kernel_launch(void* const* d_in, const int* in_sizes, int n_in,
                              void* d_out, int out_size, void* d_ws, size_t ws_size,
                              hipStream_t stream) {
    const float* x      = (const float*)d_in[0];
    const float* weight = (const float*)d_in[1];
    const float* bias   = (const float*)d_in[2];
    const float* w_off  = (const float*)d_in[3];
    const float* b_off  = (const float*)d_in[4];
    float* out = (float*)d_out;
    char* ws = (char*)d_ws;

    unsigned short* xn  = (unsigned short*)(ws + XN_OFF);
    unsigned short* wp  = (unsigned short*)(ws + WP_OFF);
    unsigned short* wpo = (unsigned short*)(ws + WPO_OFF);
    float* om = (float*)(ws + OM_OFF);
    float* py = (float*)(ws + PY_OFF);
    float* px = (float*)(ws + PX_OFF);
    float* mk = (float*)(ws + MK_OFF);

    pack_x  <<<2048, 256, 0, stream>>>(x, xn);
    pack_w  <<<KTOT*NO/256,  256, 0, stream>>>(weight, wp);
    pack_wo <<<KTOT*32/256,  256, 0, stream>>>(w_off, wpo);
    off_conv<<<1024, 128, 0, stream>>>(xn, wpo, om);
    coords_k<<<NB*9*NPIX/256, 256, 0, stream>>>(om, b_off, py, px, mk);
    dcn_main<<<1024, 256, 0, stream>>>(xn, wp, py, px, mk, bias, out);
}

// Round 4
// 264.037 us; speedup vs baseline: 1.0366x; 1.0366x over previous
//
#include <hip/hip_runtime.h>
#include <hip/hip_bf16.h>
#include <stdint.h>

typedef short bf16x8 __attribute__((ext_vector_type(8)));
typedef float f32x4  __attribute__((ext_vector_type(4)));
typedef int   i32x4  __attribute__((ext_vector_type(4)));

#define NB   8
#define NC   256
#define NO   256
#define HH   64
#define WW   64
#define NPIX 4096
#define KTOT 2304
#define NKC  72

// workspace layout (bytes)
#define XN_OFF  0u
#define XN_SZ   (NB*NPIX*NC*2u)
#define WP_OFF  (XN_OFF + XN_SZ)
#define WP_SZ   (KTOT*NO*2u)
#define WPO_OFF (WP_OFF + WP_SZ)
#define WPO_SZ  (KTOT*32u*2u)
#define OM_OFF  (WPO_OFF + WPO_SZ)
#define OM_SZ   (NB*NPIX*32u*4u)
#define PY_OFF  (OM_OFF + OM_SZ)
#define CO_SZ   (NB*9u*NPIX*4u)
#define PX_OFF  (PY_OFF + CO_SZ)
#define MK_OFF  (PX_OFF + CO_SZ)

__device__ __forceinline__ float b2f(short s) {
    union { unsigned u; float f; } z; z.u = ((unsigned)(unsigned short)s) << 16; return z.f;
}
__device__ __forceinline__ short f2b(float f) {
    __hip_bfloat16 h = __float2bfloat16(f);
    short s; __builtin_memcpy(&s, &h, 2); return s;
}
__device__ __forceinline__ float dw_lo(int u) {   // bf16 in low 16 -> f32
    union { int i; float f; } z; z.i = u << 16; return z.f;
}
__device__ __forceinline__ float dw_hi(int u) {   // bf16 in high 16 -> f32
    union { int i; float f; } z; z.i = u & 0xFFFF0000; return z.f;
}

// blend 4 corner bf16x8 vectors with weights -> bf16x8 (RNE via v_cvt_pk_bf16_f32)
__device__ __forceinline__ bf16x8 blend4(bf16x8 c0, bf16x8 c1, bf16x8 c2, bf16x8 c3,
                                         float w0, float w1, float w2, float w3) {
    union U { bf16x8 s; i32x4 i; } u0, u1, u2, u3, r;
    u0.s = c0; u1.s = c1; u2.s = c2; u3.s = c3;
#pragma unroll
    for (int d = 0; d < 4; ++d) {
        float lo = w0*dw_lo(u0.i[d]) + w1*dw_lo(u1.i[d]) + w2*dw_lo(u2.i[d]) + w3*dw_lo(u3.i[d]);
        float hi = w0*dw_hi(u0.i[d]) + w1*dw_hi(u1.i[d]) + w2*dw_hi(u2.i[d]) + w3*dw_hi(u3.i[d]);
        int pk;
        asm("v_cvt_pk_bf16_f32 %0, %1, %2" : "=v"(pk) : "v"(lo), "v"(hi));
        r.i[d] = pk;
    }
    return r.s;
}

// ---------------- kernel 1: x (NCHW f32) -> xn (NHWC bf16), vectorized ----------------
__global__ void pack_x(const float* __restrict__ x, unsigned short* __restrict__ xn) {
    __shared__ float tile[64][65];
    int blk = blockIdx.x;                  // 2048 = 8b * 4ct * 64pt
    int pt = blk & 63, ct = (blk >> 6) & 3, b = blk >> 8;
    int t = threadIdx.x;
    int ci = t >> 4, p4 = (t & 15) * 4;
    const float* src = x + ((size_t)(b*NC + ct*64))*NPIX + (size_t)pt*64;
#pragma unroll
    for (int j = 0; j < 4; ++j) {
        f32x4 v = *(const f32x4*)(src + (size_t)(ci + 16*j)*NPIX + p4);
        tile[ci + 16*j][p4+0] = v[0];
        tile[ci + 16*j][p4+1] = v[1];
        tile[ci + 16*j][p4+2] = v[2];
        tile[ci + 16*j][p4+3] = v[3];
    }
    __syncthreads();
    int c8 = (t & 7) * 8, pj0 = t >> 3;
    unsigned short* dst = xn + ((size_t)b*NPIX + (size_t)pt*64)*NC + ct*64 + c8;
#pragma unroll
    for (int j = 0; j < 2; ++j) {
        int pj = pj0 + 32*j;
        bf16x8 o;
#pragma unroll
        for (int e = 0; e < 8; ++e) o[e] = f2b(tile[c8 + e][pj]);
        *(bf16x8*)(dst + (size_t)pj*NC) = o;
    }
}

// ---------------- kernel 2: pack main weight into B-fragment order ----------------
// flat = ((kc*16 + nt)*64 + l)*8 + e ; value = W[k][o], k = kc*32 + 8*(l>>4) + e
__global__ void pack_w(const float* __restrict__ weight, unsigned short* __restrict__ wp) {
    int idx = blockIdx.x*256 + threadIdx.x;
    int e = idx & 7, l = (idx >> 3) & 63, nt = (idx >> 9) & 15, kc = idx >> 13;
    int k  = kc*32 + 8*(l >> 4) + e;
    int k2 = k >> 8, c = k & 255;
    int ky = k2 / 3, kx = k2 - 3*ky;
    int o  = nt*16 + (l & 15);
    float v = weight[(size_t)(o*NC + c)*9 + ky*3 + kx];
    wp[idx] = (unsigned short)f2b(v);
}

// ---------------- kernel 3: pack offset-conv weight (N padded 27->32) ----------------
__global__ void pack_wo(const float* __restrict__ w_off, unsigned short* __restrict__ wpo) {
    int idx = blockIdx.x*256 + threadIdx.x;
    int e = idx & 7, l = (idx >> 3) & 63, nt = (idx >> 9) & 1, kc = idx >> 10;
    int k  = kc*32 + 8*(l >> 4) + e;
    int k2 = k >> 8, c = k & 255;
    int ky = k2 / 3, kx = k2 - 3*ky;
    int n  = nt*16 + (l & 15);
    float v = (n < 27) ? w_off[(size_t)(n*NC + c)*9 + ky*3 + kx] : 0.0f;
    wpo[idx] = (unsigned short)f2b(v);
}

// ---------------- kernel 4: offset conv — no LDS, no barriers, compiler-pipelined ----
__launch_bounds__(256, 4)
__global__ void off_conv(const unsigned short* __restrict__ xn,
                         const unsigned short* __restrict__ wpo,
                         float* __restrict__ om) {
    int bid = blockIdx.x;                 // 512 = 8 batches x 64 M-tiles
    int b = bid & 7, mt = bid >> 3;
    int t = threadIdx.x, wv = t >> 6, l = t & 63, g = l >> 4;
    int pix = mt*64 + wv*16 + (l & 15);
    int y = pix >> 6, xx = pix & 63;
    f32x4 acc0 = {0.f,0.f,0.f,0.f}, acc1 = {0.f,0.f,0.f,0.f};
    const char* xc = (const char*)(xn + (size_t)b*NPIX*NC);
    const bf16x8* wpf = (const bf16x8*)wpo;
    const bf16x8 zero8 = {0,0,0,0,0,0,0,0};
#pragma unroll
    for (int kc = 0; kc < NKC; ++kc) {
        int k2 = kc >> 3, cc = kc & 7;
        int ky = k2 / 3, kx = k2 - 3*ky;
        int sy = y + ky - 1, sx = xx + kx - 1;
        bool valid = (sy>=0)&(sy<HH)&(sx>=0)&(sx<WW);
        int cs = min(max(sy,0),HH-1)*WW + min(max(sx,0),WW-1);
        bf16x8 a = *(const bf16x8*)(xc + ((size_t)cs*NC + cc*32 + g*8)*2);
        bf16x8 w0 = wpf[(size_t)(kc*2  )*64 + l];
        bf16x8 w1 = wpf[(size_t)(kc*2+1)*64 + l];
        bf16x8 au = valid ? a : zero8;
        acc0 = __builtin_amdgcn_mfma_f32_16x16x32_bf16(au, w0, acc0, 0, 0, 0);
        acc1 = __builtin_amdgcn_mfma_f32_16x16x32_bf16(au, w1, acc1, 0, 0, 0);
    }
#pragma unroll
    for (int r = 0; r < 4; ++r) {
        int pm = mt*64 + wv*16 + 4*g + r;
        om[((size_t)b*NPIX + pm)*32 +      (l & 15)] = acc0[r];
        om[((size_t)b*NPIX + pm)*32 + 16 + (l & 15)] = acc1[r];
    }
}

// ---------------- kernel 5: om -> sampling coords (py, px, mask) ----------------
__global__ void coords_k(const float* __restrict__ om, const float* __restrict__ b_off,
                         float* __restrict__ py, float* __restrict__ px,
                         float* __restrict__ mk) {
    int idx = blockIdx.x*256 + threadIdx.x;
    if (idx >= NB*9*NPIX) return;
    int pix = idx & 4095;
    int k   = (idx >> 12) % 9;
    int b   = idx / (9*NPIX);
    const float* omp = om + ((size_t)b*NPIX + pix)*32;
    float dy = omp[2*k]     + b_off[2*k];
    float dx = omp[2*k + 1] + b_off[2*k + 1];
    float m  = omp[18 + k]  + b_off[18 + k];
    float yy = (float)(pix >> 6) - 1.0f + (float)(k / 3) + dy;
    float xv = (float)(pix & 63) - 1.0f + (float)(k % 3) + dx;
    py[idx] = yy;
    px[idx] = xv;
    mk[idx] = 1.0f / (1.0f + __expf(-m));
}

// ---------------- kernel 6: main deformable conv -----------------------------------
// 512 blocks = 8 batch x 32 M-tiles x 2 N-halves. Block: 4 waves, M=128, N=128.
// Wave: M=32 (2 A-frags, reuse r=2) x N=128 (8 W-frags) -> 16 MFMA / K32-step.
// 18 phases (half-k2, 4 K-steps each); W chunk 32KB double-buffered via
// global_load_lds; ONE __syncthreads per phase; compiler schedules everything else.
__launch_bounds__(256, 2)
__global__ void dcn_main(const unsigned short* __restrict__ xn,
                         const unsigned short* __restrict__ wpack,
                         const float* __restrict__ pyA,
                         const float* __restrict__ pxA,
                         const float* __restrict__ mkA,
                         const float* __restrict__ bias,
                         float* __restrict__ out) {
    __shared__ char lds[2][32768];
    int bid = blockIdx.x;
    int b  = bid & 7;                     // batch per XCD
    int u  = bid >> 3;                    // 0..63
    int nh = u & 1, mt = u >> 1;          // N-half, M-tile 0..31
    int t = threadIdx.x, wv = t >> 6, l = t & 63, g = l >> 4;
    int pix0 = mt*128 + wv*32 + (l & 15); // frag f adds +f*16

    f32x4 acc[2][8];
#pragma unroll
    for (int f = 0; f < 2; ++f)
#pragma unroll
        for (int nt = 0; nt < 8; ++nt) acc[f][nt] = f32x4{0.f,0.f,0.f,0.f};

    const char* xc = (const char*)(xn + (size_t)b*NPIX*NC);

    auto coord_compute = [&](float py, float px, float m, float* cwf, const char** bpf) {
        float y0f = floorf(py), x0f = floorf(px);
        float ly = py - y0f, lx = px - x0f;
        int iy0 = (int)y0f, ix0 = (int)x0f;
        int iy1 = iy0 + 1,  ix1 = ix0 + 1;
        bool vy0 = (iy0 >= 0) & (iy0 < HH);
        bool vy1 = (iy1 >= 0) & (iy1 < HH);
        bool vx0 = (ix0 >= 0) & (ix0 < WW);
        bool vx1 = (ix1 >= 0) & (ix1 < WW);
        float wy0 = (1.f - ly) * m, wy1 = ly * m;
        cwf[0] = (vy0 & vx0) ? wy0 * (1.f - lx) : 0.f;
        cwf[1] = (vy0 & vx1) ? wy0 * lx         : 0.f;
        cwf[2] = (vy1 & vx0) ? wy1 * (1.f - lx) : 0.f;
        cwf[3] = (vy1 & vx1) ? wy1 * lx         : 0.f;
        int cy0 = min(max(iy0,0),HH-1), cy1 = min(max(iy1,0),HH-1);
        int cx0 = min(max(ix0,0),WW-1), cx1 = min(max(ix1,0),WW-1);
        bpf[0] = xc + ((size_t)(cy0*WW + cx0)*NC + g*8)*2;
        bpf[1] = xc + ((size_t)(cy0*WW + cx1)*NC + g*8)*2;
        bpf[2] = xc + ((size_t)(cy1*WW + cx0)*NC + g*8)*2;
        bpf[3] = xc + ((size_t)(cy1*WW + cx1)*NC + g*8)*2;
    };

    // stage phase ph's 32KB W chunk into lds[buf]; each wave stages one 8KB piece
    auto stage = [&](int buf, int ph) {
        int k2 = ph >> 1, h = ph & 1;
        int kcp = k2*8 + h*4 + wv;                        // this wave's K32-chunk
        const unsigned short* gs = wpack + ((size_t)(kcp*16 + nh*8))*512 + l*8;
        char* ld = &lds[buf][wv*8192];
#pragma unroll
        for (int i = 0; i < 8; ++i) {
            __builtin_amdgcn_global_load_lds(
                (const __attribute__((address_space(1))) unsigned int*)(gs + i*512),
                (__attribute__((address_space(3))) unsigned int*)(ld + i*1024),
                16, 0, 0);
        }
    };

    stage(0, 0);
    __syncthreads();

    for (int ph = 0; ph < 18; ++ph) {
        int buf = ph & 1;
        if (ph < 17) stage(buf ^ 1, ph + 1);
        int k2 = ph >> 1, h = ph & 1;

        float cw[2][4]; const char* bp[2][4];
#pragma unroll
        for (int f = 0; f < 2; ++f) {
            int ci = ((b*9 + k2) << 12) + pix0 + f*16;
            coord_compute(pyA[ci], pxA[ci], mkA[ci], cw[f], bp[f]);
        }
#pragma unroll
        for (int s = 0; s < 4; ++s) {
            int cb = (h*4 + s)*64;                        // channel byte offset
            bf16x8 af[2];
#pragma unroll
            for (int f = 0; f < 2; ++f) {
                bf16x8 c0 = *(const bf16x8*)(bp[f][0] + cb);
                bf16x8 c1 = *(const bf16x8*)(bp[f][1] + cb);
                bf16x8 c2 = *(const bf16x8*)(bp[f][2] + cb);
                bf16x8 c3 = *(const bf16x8*)(bp[f][3] + cb);
                af[f] = blend4(c0, c1, c2, c3, cw[f][0], cw[f][1], cw[f][2], cw[f][3]);
            }
            const char* blp = &lds[buf][s*8192];
#pragma unroll
            for (int nt = 0; nt < 8; ++nt) {
                bf16x8 wf = *(const bf16x8*)(blp + nt*1024 + l*16);
                acc[0][nt] = __builtin_amdgcn_mfma_f32_16x16x32_bf16(af[0], wf, acc[0][nt], 0, 0, 0);
                acc[1][nt] = __builtin_amdgcn_mfma_f32_16x16x32_bf16(af[1], wf, acc[1][nt], 0, 0, 0);
            }
        }
        __syncthreads();
    }

    int pmbase = mt*128 + wv*32 + 4*g;
#pragma unroll
    for (int f = 0; f < 2; ++f)
#pragma unroll
        for (int nt = 0; nt < 8; ++nt) {
            int o = nh*128 + nt*16 + (l & 15);
            float bv = bias[o];
            f32x4 r = acc[f][nt] + bv;
            *(f32x4*)(out + ((size_t)(b*NO + o))*NPIX + pmbase + f*16) = r;
        }
}

extern "C" void kernel_launch(void* const* d_in, const int* in_sizes, int n_in,
                              void* d_out, int out_size, void* d_ws, size_t ws_size,
                              hipStream_t stream) {
    const float* x      = (const float*)d_in[0];
    const float* weight = (const float*)d_in[1];
    const float* bias   = (const float*)d_in[2];
    const float* w_off  = (const float*)d_in[3];
    const float* b_off  = (const float*)d_in[4];
    float* out = (float*)d_out;
    char* ws = (char*)d_ws;

    unsigned short* xn  = (unsigned short*)(ws + XN_OFF);
    unsigned short* wp  = (unsigned short*)(ws + WP_OFF);
    unsigned short* wpo = (unsigned short*)(ws + WPO_OFF);
    float* om = (float*)(ws + OM_OFF);
    float* py = (float*)(ws + PY_OFF);
    float* px = (float*)(ws + PX_OFF);
    float* mk = (float*)(ws + MK_OFF);

    pack_x  <<<2048, 256, 0, stream>>>(x, xn);
    pack_w  <<<KTOT*NO/256,  256, 0, stream>>>(weight, wp);
    pack_wo <<<KTOT*32/256,  256, 0, stream>>>(w_off, wpo);
    off_conv<<<512, 256, 0, stream>>>(xn, wpo, om);
    coords_k<<<NB*9*NPIX/256, 256, 0, stream>>>(om, b_off, py, px, mk);
    dcn_main<<<512, 256, 0, stream>>>(xn, wp, py, px, mk, bias, out);
}